// Round 2
// baseline (251.494 us; speedup 1.0000x reference)
//
#include <hip/hip_runtime.h>
#include <stdint.h>
#include <stddef.h>

// DecoderMHA: x[4,2048,1024] fp32 -> out fp32 [4,2048,1024]
// cvt(fused) -> QKV gemm (pipelined, V transposed via LDS epilogue) ->
// flash attn (256-row q-tile, 64-key tiles, 32 q-rows/wave) -> out proj.
//
// GEMM: 128x256 tile, BK=64, 8 waves, triple-buffered LDS (144KB),
// counted-vmcnt deep pipeline, XOR chunk swizzle, setprio, XCD-grouped remap.
//
// Attn: 256 blocks x 512 thr, 8 waves x 32 q-rows share a 256-row q-tile.
// 64-key double-buffered K/V tiles (8KB each, 128B rows, 3-bit XOR chunk
// swizzle -> conflict-free b128 reads). Each wave's Kf/Vf reads amortize over
// 2 query groups (halves LDS traffic/row vs 16-row waves). Causal pairing
// (t,7-t): every block exactly 36 key-tiles. 8 bh/XCD => K/V fits one L2.

typedef __bf16 bf16;
typedef __bf16 bf16x8 __attribute__((ext_vector_type(8)));
typedef __bf16 bf16x4 __attribute__((ext_vector_type(4)));
typedef float f32x4 __attribute__((ext_vector_type(4)));

#define DM   1024
#define NH   16
#define DK   64
#define BSZ  4
#define SEQL 2048
#define NTOK 8192   // BSZ*SEQL
#define NEGB -3.0e38f

__device__ __forceinline__ void async16(const bf16* g, void* l) {
  __builtin_amdgcn_global_load_lds(
      (__attribute__((address_space(1))) void*)g,
      (__attribute__((address_space(3))) void*)l, 16, 0, 0);
}

// ---------------- fused converts: x->bf16, W*4->bf16, pad->float bias ----------
__global__ __launch_bounds__(256) void cvt_all(
    const float* __restrict__ x,
    const float* __restrict__ w0, const float* __restrict__ w1,
    const float* __restrict__ w2, const float* __restrict__ w3,
    const int* __restrict__ pad,
    bf16* __restrict__ xd,
    bf16* __restrict__ d0, bf16* __restrict__ d1,
    bf16* __restrict__ d2, bf16* __restrict__ d3,
    float* __restrict__ padf) {
  int blk = blockIdx.x;
  if (blk >= 6144) {  // pad bias: 4 blocks x 2048 entries
    int i = (blk - 6144) * 2048 + threadIdx.x * 8;
    int4 p0 = *(const int4*)(pad + i);
    int4 p1 = *(const int4*)(pad + i + 4);
    float4 o0 = {p0.x ? NEGB : 0.f, p0.y ? NEGB : 0.f, p0.z ? NEGB : 0.f, p0.w ? NEGB : 0.f};
    float4 o1 = {p1.x ? NEGB : 0.f, p1.y ? NEGB : 0.f, p1.z ? NEGB : 0.f, p1.w ? NEGB : 0.f};
    *(float4*)(padf + i) = o0;
    *(float4*)(padf + i + 4) = o1;
    return;
  }
  const float* s; bf16* d; int i;
  if (blk < 4096) { s = x; d = xd; i = blk * 2048 + threadIdx.x * 8; }
  else {
    int m = (blk - 4096) >> 9, bi = (blk - 4096) & 511;
    switch (m) {
      case 0:  s = w0; d = d0; break;
      case 1:  s = w1; d = d1; break;
      case 2:  s = w2; d = d2; break;
      default: s = w3; d = d3; break;
    }
    i = bi * 2048 + threadIdx.x * 8;
  }
  float4 v0 = *(const float4*)(s + i);
  float4 v1 = *(const float4*)(s + i + 4);
  bf16x8 o = {(bf16)v0.x, (bf16)v0.y, (bf16)v0.z, (bf16)v0.w,
              (bf16)v1.x, (bf16)v1.y, (bf16)v1.z, (bf16)v1.w};
  *(bf16x8*)(d + i) = o;
}

// ---------------- 128x256 bf16 pipelined GEMM (C = A @ W^T + bias) -------------
// OUT_MODE 0: bf16 out head-split [B,H,S,dk]; 1: fp32 flat [M,1024];
// OUT_MODE 2: bf16 out TRANSPOSED head-split [B,H,dk,S] via per-wave LDS transpose.
template <int OUT_MODE>
__device__ __forceinline__ void gemm_core(const bf16* __restrict__ A,
                                          const bf16* __restrict__ W,
                                          const float* __restrict__ bias,
                                          void* __restrict__ outp,
                                          int bm, int bn, char* smem) {
  const int tid  = threadIdx.x;
  const int lane = tid & 63;
  const int wv   = tid >> 6;     // 0..7
  const int wr   = wv >> 2;      // 0..1  (M half)
  const int wc   = wv & 3;       // 0..3  (N quarter)
  const int c    = lane & 15;
  const int quad = lane >> 4;

  const int sr = tid >> 3;                        // 0..63
  const int sj = ((tid & 7) ^ (sr & 7)) << 3;     // pre-swizzled source column
  const bf16* gA = A + (size_t)(bm + sr) * DM + sj;
  const bf16* gB = W + (size_t)(bn + sr) * DM + sj;

#define STAGE_A(TT, TGT) {                                        \
    char* la_ = smem + (TGT) * 49152 + tid * 16;                  \
    async16(gA + (size_t)(TT) * 64, la_);                         \
    async16(gA + (size_t)64 * DM + (size_t)(TT) * 64, la_ + 8192); }
#define STAGE_B(TT, TGT) {                                        \
    char* lb_ = smem + (TGT) * 49152 + 16384 + tid * 16;          \
    async16(gB + (size_t)(TT) * 64, lb_);                         \
    async16(gB + (size_t)64 * DM + (size_t)(TT) * 64, lb_ + 8192);  \
    async16(gB + (size_t)128 * DM + (size_t)(TT) * 64, lb_ + 16384); \
    async16(gB + (size_t)192 * DM + (size_t)(TT) * 64, lb_ + 24576); }

  int aoff[2][4], boff[2][4];
#pragma unroll
  for (int kk = 0; kk < 2; ++kk) {
    const int sw = ((kk * 4 + quad) ^ (c & 7)) << 4;
#pragma unroll
    for (int i = 0; i < 4; ++i) {
      aoff[kk][i] = (wr * 64 + i * 16 + c) * 128 + sw;
      boff[kk][i] = 16384 + (wc * 64 + i * 16 + c) * 128 + sw;
    }
  }

  f32x4 acc[4][4] = {};

  STAGE_A(0, 0) STAGE_B(0, 0)
  STAGE_A(1, 1) STAGE_B(1, 1)
  asm volatile("s_waitcnt vmcnt(6)" ::: "memory");
  __builtin_amdgcn_s_barrier();
  __builtin_amdgcn_sched_barrier(0);

#pragma unroll
  for (int T = 0; T < 16; ++T) {
    const char* bufc = smem + (T % 3) * 49152;
    const int TGT = (T + 2) % 3;
    bf16x8 a0[4], b0[4], a1[4], b1[4];
#pragma unroll
    for (int i = 0; i < 4; ++i) a0[i] = *(const bf16x8*)(bufc + aoff[0][i]);
#pragma unroll
    for (int i = 0; i < 4; ++i) b0[i] = *(const bf16x8*)(bufc + boff[0][i]);
    __builtin_amdgcn_sched_barrier(0);  // pin kk0 reads ahead of kk1 (lgkm count)
#pragma unroll
    for (int i = 0; i < 4; ++i) a1[i] = *(const bf16x8*)(bufc + aoff[1][i]);
#pragma unroll
    for (int i = 0; i < 4; ++i) b1[i] = *(const bf16x8*)(bufc + boff[1][i]);
    if (T < 14) { STAGE_A(T + 2, TGT) STAGE_B(T + 2, TGT) }
    __builtin_amdgcn_s_barrier();
    asm volatile("s_waitcnt lgkmcnt(8)" ::: "memory");
    __builtin_amdgcn_sched_barrier(0);
    __builtin_amdgcn_s_setprio(1);
#pragma unroll
    for (int mi = 0; mi < 4; ++mi)
#pragma unroll
      for (int ni = 0; ni < 4; ++ni)
        acc[mi][ni] = __builtin_amdgcn_mfma_f32_16x16x32_bf16(a0[mi], b0[ni],
                                                              acc[mi][ni], 0, 0, 0);
    __builtin_amdgcn_s_setprio(0);
    asm volatile("s_waitcnt lgkmcnt(0)" ::: "memory");
    __builtin_amdgcn_sched_barrier(0);
    __builtin_amdgcn_s_setprio(1);
#pragma unroll
    for (int mi = 0; mi < 4; ++mi)
#pragma unroll
      for (int ni = 0; ni < 4; ++ni)
        acc[mi][ni] = __builtin_amdgcn_mfma_f32_16x16x32_bf16(a1[mi], b1[ni],
                                                              acc[mi][ni], 0, 0, 0);
    __builtin_amdgcn_s_setprio(0);
    if (T < 14)       asm volatile("s_waitcnt vmcnt(6)" ::: "memory");
    else if (T == 14) asm volatile("s_waitcnt vmcnt(0)" ::: "memory");
    __builtin_amdgcn_s_barrier();
    __builtin_amdgcn_sched_barrier(0);
  }
#undef STAGE_A
#undef STAGE_B

  float bias_r[4];
#pragma unroll
  for (int ni = 0; ni < 4; ++ni) bias_r[ni] = bias[bn + wc * 64 + ni * 16 + c];

  if constexpr (OUT_MODE == 2) {
    __syncthreads();
    bf16* vt = (bf16*)smem + wv * 4608;  // 64*72 elements per wave
#pragma unroll
    for (int mi = 0; mi < 4; ++mi)
#pragma unroll
      for (int ni = 0; ni < 4; ++ni) {
        bf16x4 pv = {(bf16)(acc[mi][ni][0] + bias_r[ni]),
                     (bf16)(acc[mi][ni][1] + bias_r[ni]),
                     (bf16)(acc[mi][ni][2] + bias_r[ni]),
                     (bf16)(acc[mi][ni][3] + bias_r[ni])};
        *(bf16x4*)&vt[(ni * 16 + c) * 72 + mi * 16 + quad * 4] = pv;
      }
    const int base = bm + wr * 64;
    const int bb = base >> 11, s0 = base & 2047;
    const int rl = lane >> 3, cl = lane & 7;
#pragma unroll
    for (int it = 0; it < 8; ++it) {
      int d_row = it * 8 + rl;
      bf16x8 v = *(const bf16x8*)&vt[d_row * 72 + cl * 8];
      int n_g = bn + wc * 64 + d_row;
      int hh = n_g >> 6, dd = n_g & 63;
      *(bf16x8*)&((bf16*)outp)[(((size_t)(bb * NH + hh)) * DK + dd) * SEQL + s0 + cl * 8] = v;
    }
    return;
  }

#pragma unroll
  for (int mi = 0; mi < 4; ++mi) {
#pragma unroll
    for (int reg = 0; reg < 4; ++reg) {
      int m_g = bm + wr * 64 + mi * 16 + quad * 4 + reg;
#pragma unroll
      for (int ni = 0; ni < 4; ++ni) {
        int n_g = bn + wc * 64 + ni * 16 + c;
        float v = acc[mi][ni][reg] + bias_r[ni];
        if (OUT_MODE == 0) {
          int b = m_g >> 11, s = m_g & 2047;
          int h = n_g >> 6, d = n_g & 63;
          ((bf16*)outp)[(((size_t)(b * NH + h) * SEQL + s) << 6) + d] = (bf16)v;
        } else {
          ((float*)outp)[(size_t)m_g * DM + n_g] = v;
        }
      }
    }
  }
}

__global__ __launch_bounds__(512, 2) void qkv_gemm(
    const bf16* __restrict__ X,
    const bf16* __restrict__ Wq, const bf16* __restrict__ Wk, const bf16* __restrict__ Wv,
    const float* __restrict__ bq, const float* __restrict__ bk, const float* __restrict__ bv,
    bf16* __restrict__ Q, bf16* __restrict__ K, bf16* __restrict__ Vt) {
  __shared__ alignas(16) char smem[147456];
  const int f = blockIdx.x;
  const int wg = (f & 7) * 96 + (f >> 3);  // bijective: 768 % 8 == 0
  const int y = wg / 12, t = wg % 12;
  const int z = t >> 2, x = t & 3;
  const int bm = y * 128, bn = x * 256;
  if (z < 2)
    gemm_core<0>(X, z ? Wk : Wq, z ? bk : bq, z ? (void*)K : (void*)Q, bm, bn, smem);
  else
    gemm_core<2>(X, Wv, bv, Vt, bm, bn, smem);
}

__global__ __launch_bounds__(512, 2) void out_gemm(const bf16* __restrict__ A,
                                                   const bf16* __restrict__ W,
                                                   const float* __restrict__ bias,
                                                   float* __restrict__ out) {
  __shared__ alignas(16) char smem[147456];
  const int f = blockIdx.x;
  const int wg = (f & 7) * 32 + (f >> 3);
  gemm_core<1>(A, W, bias, out, (wg >> 2) * 128, (wg & 3) * 256, smem);
}

// ---------------- flash attention: 8 waves x 32 q-rows, 256-row q-tile ----------
// 256 blocks (1/CU), causal pairing (t, 7-t): 36 x 64-key tiles per block.
// K LDS [64 key][64 d], V LDS [64 d][64 key]: both 128B rows, 3-bit XOR chunk
// swizzle (write side folded into global source address; conflict-free b128
// reads). P LDS [32 q][64 k] per wave, same XOR swizzle. Each wave's Kf/Vf
// reads feed TWO 16-query groups (LDS bytes per q-row halved vs 16-row waves).
__global__ __launch_bounds__(512, 2) void attn_kernel(
    const bf16* __restrict__ Q, const bf16* __restrict__ K,
    const bf16* __restrict__ Vt, const float* __restrict__ padf,
    bf16* __restrict__ O) {
  const int B = blockIdx.x;              // 0..255
  const int bh = (B & 7) + 8 * (B >> 5); // 8 bh per XCD (KV set = 4MB = one L2)
  const int t  = (B >> 3) & 3;           // pair index 0..3
  const int b = bh >> 4, h = bh & 15;
  const int tid  = threadIdx.x;
  const int lane = tid & 63;
  const int wv   = tid >> 6;             // 0..7
  const int c    = lane & 15;
  const int quad = lane >> 4;

  __shared__ bf16 Ks[2][64 * 64];        // [key][d], 128B rows, XOR-3 chunk swz
  __shared__ bf16 Vs[2][64 * 64];        // [d][key], 128B rows, XOR-3 chunk swz
  __shared__ bf16 Pl_all[8][32 * 64];    // per-wave P, 128B rows, XOR-3 chunk swz
  bf16* Pl = &Pl_all[wv][0];

  const bf16* Qh  = Q  + (size_t)bh * SEQL * DK;
  const bf16* Kh  = K  + (size_t)bh * SEQL * DK;
  const bf16* Vth = Vt + (size_t)bh * DK * SEQL;
  const float* pb = padf + b * SEQL;

  // staging: thread stages one 16B chunk of K and one of V per tile.
  // LDS dest linear (row sr, chunk tid&7); source chunk pre-swizzled.
  const int sr = tid >> 3;                      // 0..63
  const int sj = ((tid & 7) ^ (sr & 7)) * 8;    // swizzled source element offset
  const bf16* gK = Kh  + (size_t)sr * DK   + sj;   // + kb*DK per tile
  const bf16* gV = Vth + (size_t)sr * SEQL + sj;   // + kb per tile
  bf16* lK0 = &Ks[0][tid * 8]; bf16* lK1 = &Ks[1][tid * 8];
  bf16* lV0 = &Vs[0][tid * 8]; bf16* lV1 = &Vs[1][tid * 8];

  const float sc = 0.1803368801111204f;  // log2(e) / sqrt(64)

  for (int pass = 0; pass < 2; ++pass) {
    const int qt  = pass ? 7 - t : t;    // 256-row q-tile index
    const int R   = qt * 256 + wv * 32;  // wave's first q row
    const int nkt = (qt + 1) * 4;        // 64-key tiles

    // Q fragments (B-operand): qg = 16-query group, lane c = query
    bf16x8 Qf[2][2];
#pragma unroll
    for (int qg = 0; qg < 2; ++qg)
#pragma unroll
      for (int kh = 0; kh < 2; ++kh)
        Qf[qg][kh] = *(const bf16x8*)&Qh[(size_t)(R + qg * 16 + c) * DK + kh * 32 + quad * 8];

    f32x4 Oc[2][4] = {};
    float ls[2] = {0.f, 0.f};

    __syncthreads();  // previous pass done reading buffers
    async16(gK, lK0);
    async16(gV, lV0);

    for (int kt = 0; kt < nkt; ++kt) {
      const int cur = kt & 1;
      const int kb = kt * 64;
      __syncthreads();  // drains asyncs: buf[cur] ready; buf[cur^1] free

      if (kt + 1 < nkt) {
        async16(gK + (size_t)(kt + 1) * 64 * DK, cur ? lK0 : lK1);
        async16(gV + (size_t)(kt + 1) * 64,      cur ? lV0 : lV1);
      }
      if (kb > R + 31) continue;  // fully masked for this wave

      float4 bc[4];
#pragma unroll
      for (int kf = 0; kf < 4; ++kf)
        bc[kf] = *(const float4*)&pb[kb + kf * 16 + quad * 4];

      const bf16* Kc = cur ? Ks[1] : Ks[0];
      const bf16* Vc = cur ? Vs[1] : Vs[0];

      // LDS -> fragments (shared across both query groups)
      bf16x8 Kf[4][2], Vf[4][2];
#pragma unroll
      for (int kf = 0; kf < 4; ++kf)
#pragma unroll
        for (int kh = 0; kh < 2; ++kh)
          Kf[kf][kh] = *(const bf16x8*)&Kc[(kf * 16 + c) * 64 + (((kh * 4 + quad) ^ (c & 7)) * 8)];
#pragma unroll
      for (int df = 0; df < 4; ++df)
#pragma unroll
        for (int kv = 0; kv < 2; ++kv)
          Vf[df][kv] = *(const bf16x8*)&Vc[(df * 16 + c) * 64 + (((kv * 4 + quad) ^ (c & 7)) * 8)];

      // S^T = K.Q^T  (col=query, row=key); st[qg][kf]: key = kf*16 + quad*4 + r
      f32x4 st[2][4] = {};
#pragma unroll
      for (int qg = 0; qg < 2; ++qg)
#pragma unroll
        for (int kh = 0; kh < 2; ++kh)
#pragma unroll
          for (int kf = 0; kf < 4; ++kf)
            st[qg][kf] = __builtin_amdgcn_mfma_f32_16x16x32_bf16(Kf[kf][kh], Qf[qg][kh],
                                                                 st[qg][kf], 0, 0, 0);

      // softmax (no max-subtraction) + P store; masked keys -> exp2(-3e38)=0
      const bool dg = (kb + 63 > R);
#pragma unroll
      for (int qg = 0; qg < 2; ++qg) {
        const int qrow = R + qg * 16 + c;
#pragma unroll
        for (int kf = 0; kf < 4; ++kf) {
          const float* bv4 = (const float*)&bc[kf];
          float p4[4];
#pragma unroll
          for (int r = 0; r < 4; ++r) {
            float e = __builtin_amdgcn_exp2f(__builtin_fmaf(st[qg][kf][r], sc, bv4[r]));
            if (dg && (kb + kf * 16 + quad * 4 + r > qrow)) e = 0.f;
            p4[r] = e;
            ls[qg] += e;
          }
          bf16x4 pk = {(bf16)p4[0], (bf16)p4[1], (bf16)p4[2], (bf16)p4[3]};
          *(bf16x4*)&Pl[(qg * 16 + c) * 64 +
                        (((kf * 2 + (quad >> 1)) ^ (c & 7)) * 8) + (quad & 1) * 4] = pk;
        }
      }

      // O += P @ V   (af key order == Vf key order: quad*8 = (quad>>1)*16+(quad&1)*8)
#pragma unroll
      for (int qg = 0; qg < 2; ++qg)
#pragma unroll
        for (int kv = 0; kv < 2; ++kv) {
          bf16x8 af = *(const bf16x8*)&Pl[(qg * 16 + c) * 64 +
                                          (((kv * 4 + quad) ^ (c & 7)) * 8)];
#pragma unroll
          for (int df = 0; df < 4; ++df)
            Oc[qg][df] = __builtin_amdgcn_mfma_f32_16x16x32_bf16(af, Vf[df][kv],
                                                                 Oc[qg][df], 0, 0, 0);
        }
    }

    // epilogue: reduce l across quads, divide, store
#pragma unroll
    for (int qg = 0; qg < 2; ++qg) {
      float l = ls[qg];
      l += __shfl_xor(l, 16);
      l += __shfl_xor(l, 32);
      float linv = (l > 0.f) ? 1.f / l : 0.f;
      float lr[4];
#pragma unroll
      for (int r = 0; r < 4; ++r) lr[r] = __shfl(linv, quad * 4 + r);
#pragma unroll
      for (int r = 0; r < 4; ++r) {
        size_t row = (size_t)(b * SEQL + R + qg * 16 + quad * 4 + r) * DM + h * DK;
#pragma unroll
        for (int df = 0; df < 4; ++df)
          O[row + df * 16 + c] = (bf16)(Oc[qg][df][r] * lr[r]);
      }
    }
  }
}

// ---------------- launch ----------------
extern "C" void kernel_launch(void* const* d_in, const int* in_sizes, int n_in,
                              void* d_out, int out_size, void* d_ws, size_t ws_size,
                              hipStream_t stream) {
  const float* x   = (const float*)d_in[0];
  const int*   pad = (const int*)d_in[1];
  const float* Wq  = (const float*)d_in[2];
  const float* bq  = (const float*)d_in[3];
  const float* Wk  = (const float*)d_in[4];
  const float* bk  = (const float*)d_in[5];
  const float* Wv  = (const float*)d_in[6];
  const float* bv  = (const float*)d_in[7];
  const float* Wo  = (const float*)d_in[8];
  const float* bo  = (const float*)d_in[9];
  float* out = (float*)d_out;

  const size_t SZ_X = (size_t)NTOK * DM * 2;  // 16 MB
  const size_t SZ_W = (size_t)DM * DM * 2;    // 2 MB
  char* ws = (char*)d_ws;
  bf16* Xb  = (bf16*)ws;  ws += SZ_X;
  bf16* Wqb = (bf16*)ws;  ws += SZ_W;
  bf16* Wkb = (bf16*)ws;  ws += SZ_W;
  bf16* Wvb = (bf16*)ws;  ws += SZ_W;
  bf16* Wob = (bf16*)ws;  ws += SZ_W;
  bf16* Qb  = (bf16*)ws;  ws += SZ_X;
  bf16* Kb  = (bf16*)ws;  ws += SZ_X;
  bf16* Vtb = (bf16*)ws;  ws += SZ_X;   // [B,H,dk,S]
  bf16* Ob  = (bf16*)ws;  ws += SZ_X;
  float* padfb = (float*)ws; ws += (size_t)NTOK * 4;

  cvt_all<<<6148, 256, 0, stream>>>(x, Wq, Wk, Wv, Wo, pad,
                                    Xb, Wqb, Wkb, Wvb, Wob, padfb);
  qkv_gemm<<<768, 512, 0, stream>>>(Xb, Wqb, Wkb, Wvb, bq, bk, bv, Qb, Kb, Vtb);
  attn_kernel<<<256, 512, 0, stream>>>(Qb, Kb, Vtb, padfb, Ob);
  out_gemm<<<256, 512, 0, stream>>>(Ob, Wob, bo, out);
}

// Round 3
// 246.535 us; speedup vs baseline: 1.0201x; 1.0201x over previous
//
#include <hip/hip_runtime.h>
#include <stdint.h>
#include <stddef.h>

// DecoderMHA: x[4,2048,1024] fp32 -> out fp32 [4,2048,1024]
// cvt(fused) -> QKV gemm (fine-phase m201 schedule, V transposed epilogue) ->
// flash attn (unchanged) -> out proj (fine-phase gemm).
//
// GEMM schedule (m201 cadence): BK=32, quad-buffered LDS, per phase
// {4-8 ds_read_b128; 1-2 global_load_lds; s_barrier; lgkmcnt(0); setprio(1);
//  16 MFMA; setprio(0); s_barrier}, counted vmcnt once per K-tile (never 0
// until tail). qkv: 256x256 tile (2 phases/K-tile, 128KB LDS, vmcnt(8));
// out: 128x256 (1 phase/K-tile, 96KB LDS, vmcnt(6)).

typedef __bf16 bf16;
typedef __bf16 bf16x8 __attribute__((ext_vector_type(8)));
typedef __bf16 bf16x4 __attribute__((ext_vector_type(4)));
typedef float f32x4 __attribute__((ext_vector_type(4)));

#define DM   1024
#define NH   16
#define DK   64
#define BSZ  4
#define SEQL 2048
#define NTOK 8192   // BSZ*SEQL
#define NEGB -3.0e38f

__device__ __forceinline__ void async16(const bf16* g, void* l) {
  __builtin_amdgcn_global_load_lds(
      (__attribute__((address_space(1))) void*)g,
      (__attribute__((address_space(3))) void*)l, 16, 0, 0);
}

// ---------------- fused converts: x->bf16, W*4->bf16, pad->float bias ----------
__global__ __launch_bounds__(256) void cvt_all(
    const float* __restrict__ x,
    const float* __restrict__ w0, const float* __restrict__ w1,
    const float* __restrict__ w2, const float* __restrict__ w3,
    const int* __restrict__ pad,
    bf16* __restrict__ xd,
    bf16* __restrict__ d0, bf16* __restrict__ d1,
    bf16* __restrict__ d2, bf16* __restrict__ d3,
    float* __restrict__ padf) {
  int blk = blockIdx.x;
  if (blk >= 6144) {  // pad bias: 4 blocks x 2048 entries
    int i = (blk - 6144) * 2048 + threadIdx.x * 8;
    int4 p0 = *(const int4*)(pad + i);
    int4 p1 = *(const int4*)(pad + i + 4);
    float4 o0 = {p0.x ? NEGB : 0.f, p0.y ? NEGB : 0.f, p0.z ? NEGB : 0.f, p0.w ? NEGB : 0.f};
    float4 o1 = {p1.x ? NEGB : 0.f, p1.y ? NEGB : 0.f, p1.z ? NEGB : 0.f, p1.w ? NEGB : 0.f};
    *(float4*)(padf + i) = o0;
    *(float4*)(padf + i + 4) = o1;
    return;
  }
  const float* s; bf16* d; int i;
  if (blk < 4096) { s = x; d = xd; i = blk * 2048 + threadIdx.x * 8; }
  else {
    int m = (blk - 4096) >> 9, bi = (blk - 4096) & 511;
    switch (m) {
      case 0:  s = w0; d = d0; break;
      case 1:  s = w1; d = d1; break;
      case 2:  s = w2; d = d2; break;
      default: s = w3; d = d3; break;
    }
    i = bi * 2048 + threadIdx.x * 8;
  }
  float4 v0 = *(const float4*)(s + i);
  float4 v1 = *(const float4*)(s + i + 4);
  bf16x8 o = {(bf16)v0.x, (bf16)v0.y, (bf16)v0.z, (bf16)v0.w,
              (bf16)v1.x, (bf16)v1.y, (bf16)v1.z, (bf16)v1.w};
  *(bf16x8*)(d + i) = o;
}

// ---------------- fine-phase bf16 GEMM core (C = A @ W^T + bias) ---------------
// BM in {256,128}, BN=256, BK=32, 8 waves (2M x 4N), quad-buffered LDS.
// LDS element (r, chunk j in 0..3 of 16B): byte r*64 + (j ^ (r&3))*16 ; the
// global_load_lds dest is LINEAR in tid (dest byte = tid*16), source column
// pre-swizzled. Fragment read (row r, k-chunk quad): r*64 + (quad^(r&3))*16
// -> 8 lanes per 4-bank group = structural optimum.
// OUT_MODE 0: bf16 out head-split [B,H,S,dk]; 1: fp32 flat [M,1024];
// OUT_MODE 2: bf16 out TRANSPOSED head-split [B,H,dk,S] via per-wave LDS transpose.
template <int BM, int OUT_MODE>
__device__ __forceinline__ void gemm_fine(const bf16* __restrict__ A,
                                          const bf16* __restrict__ W,
                                          const float* __restrict__ bias,
                                          void* __restrict__ outp,
                                          int bm, int bn, char* smem) {
  constexpr int MFR  = BM / 32;        // m-frags per wave: 8 (BM=256) / 4 (128)
  constexpr int ABUF = BM * 64;        // bytes per A K-tile buffer
  const int tid  = threadIdx.x;
  const int lane = tid & 63;
  const int wv   = tid >> 6;
  const int wr   = wv >> 2;            // M half
  const int wc   = wv & 3;             // N quarter
  const int c    = lane & 15;
  const int quad = lane >> 4;

  char* Ab4 = smem;
  char* Bb4 = smem + 4 * ABUF;

  // staging: thread t owns (row = t>>2, chunk = t&3); dest = base + t*16 (linear),
  // source chunk pre-swizzled: (t&3) ^ (row&3).
  const int sr  = tid >> 2;
  const int sjj = ((tid & 3) ^ (sr & 3)) * 8;
  const bf16* gA = A + (size_t)(bm + sr) * DM + sjj;
  const bf16* gB = W + (size_t)(bn + sr) * DM + sjj;

#define STG_A(KT, U) {                                                   \
    char* la_ = Ab4 + (U) * ABUF + tid * 16;                             \
    async16(gA + (size_t)(KT) * 32, la_);                                \
    if constexpr (BM == 256)                                             \
      async16(gA + (size_t)(KT) * 32 + (size_t)128 * DM, la_ + 8192); }
#define STG_B(KT, U) {                                                   \
    char* lb_ = Bb4 + (U) * 16384 + tid * 16;                            \
    async16(gB + (size_t)(KT) * 32, lb_);                                \
    async16(gB + (size_t)(KT) * 32 + (size_t)128 * DM, lb_ + 8192); }

  const int sw = (quad ^ (c & 3)) * 16;
  int aoff[MFR], boff[4];
#pragma unroll
  for (int i = 0; i < MFR; ++i) aoff[i] = (wr * (BM / 2) + i * 16 + c) * 64 + sw;
#pragma unroll
  for (int i = 0; i < 4; ++i)   boff[i] = (wc * 64 + i * 16 + c) * 64 + sw;

  f32x4 acc[MFR][4] = {};

  // prologue: stage K-tiles 0,1,2; wait tile 0 (2 tiles stay in flight)
  STG_A(0, 0) STG_B(0, 0)
  STG_A(1, 1) STG_B(1, 1)
  STG_A(2, 2) STG_B(2, 2)
  if constexpr (BM == 256) asm volatile("s_waitcnt vmcnt(8)" ::: "memory");
  else                     asm volatile("s_waitcnt vmcnt(6)" ::: "memory");
  __builtin_amdgcn_s_barrier();
  __builtin_amdgcn_sched_barrier(0);

#pragma unroll
  for (int kt = 0; kt < 32; ++kt) {
    const char* Ac = Ab4 + (kt & 3) * ABUF;
    const char* Bc = Bb4 + (kt & 3) * 16384;
    const int u = (kt + 3) & 3;
    bf16x8 a[4], b[4];
    // phase 0: reads (a0-3, b0-3) + stage A of kt+3
#pragma unroll
    for (int i = 0; i < 4; ++i) a[i] = *(const bf16x8*)(Ac + aoff[i]);
#pragma unroll
    for (int i = 0; i < 4; ++i) b[i] = *(const bf16x8*)(Bc + boff[i]);
    if (kt + 3 < 32) STG_A(kt + 3, u)
    if constexpr (BM == 128) { if (kt + 3 < 32) STG_B(kt + 3, u) }
    __builtin_amdgcn_s_barrier();
    asm volatile("s_waitcnt lgkmcnt(0)" ::: "memory");
    __builtin_amdgcn_sched_barrier(0);
    __builtin_amdgcn_s_setprio(1);
#pragma unroll
    for (int mi = 0; mi < 4; ++mi)
#pragma unroll
      for (int ni = 0; ni < 4; ++ni)
        acc[mi][ni] = __builtin_amdgcn_mfma_f32_16x16x32_bf16(a[mi], b[ni],
                                                              acc[mi][ni], 0, 0, 0);
    __builtin_amdgcn_s_setprio(0);
    if constexpr (BM == 256) {
      // phase 1: reads (a4-7) + stage B of kt+3; b[] reused from phase 0
      __builtin_amdgcn_s_barrier();
#pragma unroll
      for (int i = 0; i < 4; ++i) a[i] = *(const bf16x8*)(Ac + aoff[4 + i]);
      if (kt + 3 < 32) STG_B(kt + 3, u)
      __builtin_amdgcn_s_barrier();
      asm volatile("s_waitcnt lgkmcnt(0)" ::: "memory");
      __builtin_amdgcn_sched_barrier(0);
      __builtin_amdgcn_s_setprio(1);
#pragma unroll
      for (int mi = 0; mi < 4; ++mi)
#pragma unroll
        for (int ni = 0; ni < 4; ++ni)
          acc[4 + mi][ni] = __builtin_amdgcn_mfma_f32_16x16x32_bf16(a[mi], b[ni],
                                                                    acc[4 + mi][ni], 0, 0, 0);
      __builtin_amdgcn_s_setprio(0);
    }
    // K-tile boundary: counted vmcnt (kt+1's loads complete; kt+2/kt+3 in flight)
    if (kt < 29) {
      if constexpr (BM == 256) asm volatile("s_waitcnt vmcnt(8)" ::: "memory");
      else                     asm volatile("s_waitcnt vmcnt(6)" ::: "memory");
    } else if (kt == 29) {
      if constexpr (BM == 256) asm volatile("s_waitcnt vmcnt(4)" ::: "memory");
      else                     asm volatile("s_waitcnt vmcnt(3)" ::: "memory");
    } else if (kt == 30) {
      asm volatile("s_waitcnt vmcnt(0)" ::: "memory");
    }
    if (kt != 31) {
      __builtin_amdgcn_s_barrier();
      __builtin_amdgcn_sched_barrier(0);
    }
  }
#undef STG_A
#undef STG_B

  float bias_r[4];
#pragma unroll
  for (int ni = 0; ni < 4; ++ni) bias_r[ni] = bias[bn + wc * 64 + ni * 16 + c];

  if constexpr (OUT_MODE == 2) {
    // per-wave 64x64 transpose in LDS, two 64-row halves; coalesced b128 stores.
    __syncthreads();  // all waves done with pipeline LDS
    bf16* vt = (bf16*)smem + wv * 4608;  // 64*72 elements per wave
#pragma unroll
    for (int mh = 0; mh < 2; ++mh) {
#pragma unroll
      for (int mi = 0; mi < 4; ++mi)
#pragma unroll
        for (int ni = 0; ni < 4; ++ni) {
          f32x4 av = acc[mh * 4 + mi][ni];
          bf16x4 pv = {(bf16)(av[0] + bias_r[ni]), (bf16)(av[1] + bias_r[ni]),
                       (bf16)(av[2] + bias_r[ni]), (bf16)(av[3] + bias_r[ni])};
          *(bf16x4*)&vt[(ni * 16 + c) * 72 + mi * 16 + quad * 4] = pv;
        }
      const int base = bm + wr * 128 + mh * 64;
      const int bb = base >> 11, s0 = base & 2047;
      const int rl = lane >> 3, cl = lane & 7;
#pragma unroll
      for (int it = 0; it < 8; ++it) {
        int d_row = it * 8 + rl;
        bf16x8 v = *(const bf16x8*)&vt[d_row * 72 + cl * 8];
        int n_g = bn + wc * 64 + d_row;
        int hh = n_g >> 6, dd = n_g & 63;
        *(bf16x8*)&((bf16*)outp)[(((size_t)(bb * NH + hh)) * DK + dd) * SEQL + s0 + cl * 8] = v;
      }
    }
    return;
  }

#pragma unroll
  for (int mi = 0; mi < MFR; ++mi) {
#pragma unroll
    for (int reg = 0; reg < 4; ++reg) {
      int m_g = bm + wr * (BM / 2) + mi * 16 + quad * 4 + reg;
#pragma unroll
      for (int ni = 0; ni < 4; ++ni) {
        int n_g = bn + wc * 64 + ni * 16 + c;
        float v = acc[mi][ni][reg] + bias_r[ni];
        if constexpr (OUT_MODE == 0) {
          int b = m_g >> 11, s = m_g & 2047;
          int h = n_g >> 6, d = n_g & 63;
          ((bf16*)outp)[(((size_t)(b * NH + h) * SEQL + s) << 6) + d] = (bf16)v;
        } else {
          ((float*)outp)[(size_t)m_g * DM + n_g] = v;
        }
      }
    }
  }
}

// QKV: 384 blocks (32 m-tiles x 4 n-tiles x 3 matrices), 256x256 tiles.
// XCD remap: xcd = f&7 gets 4 m-tiles x all (n,z); n-outer within the XCD chunk
// keeps concurrent W-tiles ~4MB (L2-resident).
__global__ __launch_bounds__(512, 2) void qkv_gemm(
    const bf16* __restrict__ X,
    const bf16* __restrict__ Wq, const bf16* __restrict__ Wk, const bf16* __restrict__ Wv,
    const float* __restrict__ bq, const float* __restrict__ bk, const float* __restrict__ bv,
    bf16* __restrict__ Q, bf16* __restrict__ K, bf16* __restrict__ Vt) {
  __shared__ alignas(16) char smem[131072];
  const int f = blockIdx.x;            // 0..383
  const int l = f >> 3;                // 0..47 within XCD
  const int np  = l / 12;              // n-tile 0..3
  const int rem = l % 12;
  const int z   = rem >> 2;            // 0:Q 1:K 2:V
  const int mp  = (f & 7) * 4 + (rem & 3);  // m-tile 0..31
  const int bm = mp * 256, bn = np * 256;
  if (z == 0)      gemm_fine<256, 0>(X, Wq, bq, Q,  bm, bn, smem);
  else if (z == 1) gemm_fine<256, 0>(X, Wk, bk, K,  bm, bn, smem);
  else             gemm_fine<256, 2>(X, Wv, bv, Vt, bm, bn, smem);
}

// Out proj: 256 blocks (64 m x 4 n), 128x256 tiles = exactly 1 block/CU round.
__global__ __launch_bounds__(512, 2) void out_gemm(const bf16* __restrict__ A,
                                                   const bf16* __restrict__ W,
                                                   const float* __restrict__ bias,
                                                   float* __restrict__ out) {
  __shared__ alignas(16) char smem[98304];
  const int f = blockIdx.x;
  const int wg = (f & 7) * 32 + (f >> 3);
  gemm_fine<128, 1>(A, W, bias, out, (wg >> 2) * 128, (wg & 3) * 256, smem);
}

// ---------------- flash attention: 8 waves x 32 q-rows, 256-row q-tile ----------
// (unchanged from previous round)
__global__ __launch_bounds__(512, 2) void attn_kernel(
    const bf16* __restrict__ Q, const bf16* __restrict__ K,
    const bf16* __restrict__ Vt, const float* __restrict__ padf,
    bf16* __restrict__ O) {
  const int B = blockIdx.x;              // 0..255
  const int bh = (B & 7) + 8 * (B >> 5); // 8 bh per XCD (KV set = 4MB = one L2)
  const int t  = (B >> 3) & 3;           // pair index 0..3
  const int b = bh >> 4, h = bh & 15;
  const int tid  = threadIdx.x;
  const int lane = tid & 63;
  const int wv   = tid >> 6;             // 0..7
  const int c    = lane & 15;
  const int quad = lane >> 4;

  __shared__ bf16 Ks[2][64 * 64];        // [key][d], 128B rows, XOR-3 chunk swz
  __shared__ bf16 Vs[2][64 * 64];        // [d][key], 128B rows, XOR-3 chunk swz
  __shared__ bf16 Pl_all[8][32 * 64];    // per-wave P, 128B rows, XOR-3 chunk swz
  bf16* Pl = &Pl_all[wv][0];

  const bf16* Qh  = Q  + (size_t)bh * SEQL * DK;
  const bf16* Kh  = K  + (size_t)bh * SEQL * DK;
  const bf16* Vth = Vt + (size_t)bh * DK * SEQL;
  const float* pb = padf + b * SEQL;

  const int sr = tid >> 3;                      // 0..63
  const int sj = ((tid & 7) ^ (sr & 7)) * 8;    // swizzled source element offset
  const bf16* gK = Kh  + (size_t)sr * DK   + sj;
  const bf16* gV = Vth + (size_t)sr * SEQL + sj;
  bf16* lK0 = &Ks[0][tid * 8]; bf16* lK1 = &Ks[1][tid * 8];
  bf16* lV0 = &Vs[0][tid * 8]; bf16* lV1 = &Vs[1][tid * 8];

  const float sc = 0.1803368801111204f;  // log2(e) / sqrt(64)

  for (int pass = 0; pass < 2; ++pass) {
    const int qt  = pass ? 7 - t : t;    // 256-row q-tile index
    const int R   = qt * 256 + wv * 32;  // wave's first q row
    const int nkt = (qt + 1) * 4;        // 64-key tiles

    bf16x8 Qf[2][2];
#pragma unroll
    for (int qg = 0; qg < 2; ++qg)
#pragma unroll
      for (int kh = 0; kh < 2; ++kh)
        Qf[qg][kh] = *(const bf16x8*)&Qh[(size_t)(R + qg * 16 + c) * DK + kh * 32 + quad * 8];

    f32x4 Oc[2][4] = {};
    float ls[2] = {0.f, 0.f};

    __syncthreads();
    async16(gK, lK0);
    async16(gV, lV0);

    for (int kt = 0; kt < nkt; ++kt) {
      const int cur = kt & 1;
      const int kb = kt * 64;
      __syncthreads();

      if (kt + 1 < nkt) {
        async16(gK + (size_t)(kt + 1) * 64 * DK, cur ? lK0 : lK1);
        async16(gV + (size_t)(kt + 1) * 64,      cur ? lV0 : lV1);
      }
      if (kb > R + 31) continue;

      float4 bc[4];
#pragma unroll
      for (int kf = 0; kf < 4; ++kf)
        bc[kf] = *(const float4*)&pb[kb + kf * 16 + quad * 4];

      const bf16* Kc = cur ? Ks[1] : Ks[0];
      const bf16* Vc = cur ? Vs[1] : Vs[0];

      bf16x8 Kf[4][2], Vf[4][2];
#pragma unroll
      for (int kf = 0; kf < 4; ++kf)
#pragma unroll
        for (int kh = 0; kh < 2; ++kh)
          Kf[kf][kh] = *(const bf16x8*)&Kc[(kf * 16 + c) * 64 + (((kh * 4 + quad) ^ (c & 7)) * 8)];
#pragma unroll
      for (int df = 0; df < 4; ++df)
#pragma unroll
        for (int kv = 0; kv < 2; ++kv)
          Vf[df][kv] = *(const bf16x8*)&Vc[(df * 16 + c) * 64 + (((kv * 4 + quad) ^ (c & 7)) * 8)];

      f32x4 st[2][4] = {};
#pragma unroll
      for (int qg = 0; qg < 2; ++qg)
#pragma unroll
        for (int kh = 0; kh < 2; ++kh)
#pragma unroll
          for (int kf = 0; kf < 4; ++kf)
            st[qg][kf] = __builtin_amdgcn_mfma_f32_16x16x32_bf16(Kf[kf][kh], Qf[qg][kh],
                                                                 st[qg][kf], 0, 0, 0);

      const bool dg = (kb + 63 > R);
#pragma unroll
      for (int qg = 0; qg < 2; ++qg) {
        const int qrow = R + qg * 16 + c;
#pragma unroll
        for (int kf = 0; kf < 4; ++kf) {
          const float* bv4 = (const float*)&bc[kf];
          float p4[4];
#pragma unroll
          for (int r = 0; r < 4; ++r) {
            float e = __builtin_amdgcn_exp2f(__builtin_fmaf(st[qg][kf][r], sc, bv4[r]));
            if (dg && (kb + kf * 16 + quad * 4 + r > qrow)) e = 0.f;
            p4[r] = e;
            ls[qg] += e;
          }
          bf16x4 pk = {(bf16)p4[0], (bf16)p4[1], (bf16)p4[2], (bf16)p4[3]};
          *(bf16x4*)&Pl[(qg * 16 + c) * 64 +
                        (((kf * 2 + (quad >> 1)) ^ (c & 7)) * 8) + (quad & 1) * 4] = pk;
        }
      }

#pragma unroll
      for (int qg = 0; qg < 2; ++qg)
#pragma unroll
        for (int kv = 0; kv < 2; ++kv) {
          bf16x8 af = *(const bf16x8*)&Pl[(qg * 16 + c) * 64 +
                                          (((kv * 4 + quad) ^ (c & 7)) * 8)];
#pragma unroll
          for (int df = 0; df < 4; ++df)
            Oc[qg][df] = __builtin_amdgcn_mfma_f32_16x16x32_bf16(af, Vf[df][kv],
                                                                 Oc[qg][df], 0, 0, 0);
        }
    }

#pragma unroll
    for (int qg = 0; qg < 2; ++qg) {
      float l = ls[qg];
      l += __shfl_xor(l, 16);
      l += __shfl_xor(l, 32);
      float linv = (l > 0.f) ? 1.f / l : 0.f;
      float lr[4];
#pragma unroll
      for (int r = 0; r < 4; ++r) lr[r] = __shfl(linv, quad * 4 + r);
#pragma unroll
      for (int r = 0; r < 4; ++r) {
        size_t row = (size_t)(b * SEQL + R + qg * 16 + quad * 4 + r) * DM + h * DK;
#pragma unroll
        for (int df = 0; df < 4; ++df)
          O[row + df * 16 + c] = (bf16)(Oc[qg][df][r] * lr[r]);
      }
    }
  }
}

// ---------------- launch ----------------
extern "C" void kernel_launch(void* const* d_in, const int* in_sizes, int n_in,
                              void* d_out, int out_size, void* d_ws, size_t ws_size,
                              hipStream_t stream) {
  const float* x   = (const float*)d_in[0];
  const int*   pad = (const int*)d_in[1];
  const float* Wq  = (const float*)d_in[2];
  const float* bq  = (const float*)d_in[3];
  const float* Wk  = (const float*)d_in[4];
  const float* bk  = (const float*)d_in[5];
  const float* Wv  = (const float*)d_in[6];
  const float* bv  = (const float*)d_in[7];
  const float* Wo  = (const float*)d_in[8];
  const float* bo  = (const float*)d_in[9];
  float* out = (float*)d_out;

  const size_t SZ_X = (size_t)NTOK * DM * 2;  // 16 MB
  const size_t SZ_W = (size_t)DM * DM * 2;    // 2 MB
  char* ws = (char*)d_ws;
  bf16* Xb  = (bf16*)ws;  ws += SZ_X;
  bf16* Wqb = (bf16*)ws;  ws += SZ_W;
  bf16* Wkb = (bf16*)ws;  ws += SZ_W;
  bf16* Wvb = (bf16*)ws;  ws += SZ_W;
  bf16* Wob = (bf16*)ws;  ws += SZ_W;
  bf16* Qb  = (bf16*)ws;  ws += SZ_X;
  bf16* Kb  = (bf16*)ws;  ws += SZ_X;
  bf16* Vtb = (bf16*)ws;  ws += SZ_X;   // [B,H,dk,S]
  bf16* Ob  = (bf16*)ws;  ws += SZ_X;
  float* padfb = (float*)ws; ws += (size_t)NTOK * 4;

  cvt_all<<<6148, 256, 0, stream>>>(x, Wq, Wk, Wv, Wo, pad,
                                    Xb, Wqb, Wkb, Wvb, Wob, padfb);
  qkv_gemm<<<384, 512, 0, stream>>>(Xb, Wqb, Wkb, Wvb, bq, bk, bv, Qb, Kb, Vtb);
  attn_kernel<<<256, 512, 0, stream>>>(Qb, Kb, Vtb, padfb, Ob);
  out_gemm<<<256, 512, 0, stream>>>(Ob, Wob, bo, out);
}

// Round 4
// 235.034 us; speedup vs baseline: 1.0700x; 1.0489x over previous
//
#include <hip/hip_runtime.h>
#include <stdint.h>
#include <stddef.h>

// DecoderMHA: x[4,2048,1024] fp32 -> out fp32 [4,2048,1024]
// cvt(fused) -> QKV gemm (fine-phase, 2 blocks/CU, V transposed epilogue) ->
// flash attn -> out proj (same gemm core).
//
// GEMM core: 128x256 tile, BK=32, 8 waves (2M x 4N), TRIPLE-buffered LDS
// (72KB -> 2 blocks/CU on 160KB LDS; launch_bounds(512,4) caps VGPR<=128).
// Per K-tile: {8 ds_read_b128; 3 global_load_lds (tile kt+2); s_barrier;
// lgkmcnt(0); setprio(1); 16 MFMA; setprio(0); vmcnt(3); s_barrier}.
// vmcnt(3): next tile's 3 loads retired, tile+2's 3 stay in flight; vmcnt(0)
// only at kt=30. qkv grid 768 = 3 exact rounds; out grid 256 = 1 round.

typedef __bf16 bf16;
typedef __bf16 bf16x8 __attribute__((ext_vector_type(8)));
typedef __bf16 bf16x4 __attribute__((ext_vector_type(4)));
typedef float f32x4 __attribute__((ext_vector_type(4)));

#define DM   1024
#define NH   16
#define DK   64
#define BSZ  4
#define SEQL 2048
#define NTOK 8192   // BSZ*SEQL
#define NEGB -3.0e38f

__device__ __forceinline__ void async16(const bf16* g, void* l) {
  __builtin_amdgcn_global_load_lds(
      (__attribute__((address_space(1))) void*)g,
      (__attribute__((address_space(3))) void*)l, 16, 0, 0);
}

// ---------------- fused converts: x->bf16, W*4->bf16, pad->float bias ----------
__global__ __launch_bounds__(256) void cvt_all(
    const float* __restrict__ x,
    const float* __restrict__ w0, const float* __restrict__ w1,
    const float* __restrict__ w2, const float* __restrict__ w3,
    const int* __restrict__ pad,
    bf16* __restrict__ xd,
    bf16* __restrict__ d0, bf16* __restrict__ d1,
    bf16* __restrict__ d2, bf16* __restrict__ d3,
    float* __restrict__ padf) {
  int blk = blockIdx.x;
  if (blk >= 6144) {  // pad bias: 4 blocks x 2048 entries
    int i = (blk - 6144) * 2048 + threadIdx.x * 8;
    int4 p0 = *(const int4*)(pad + i);
    int4 p1 = *(const int4*)(pad + i + 4);
    float4 o0 = {p0.x ? NEGB : 0.f, p0.y ? NEGB : 0.f, p0.z ? NEGB : 0.f, p0.w ? NEGB : 0.f};
    float4 o1 = {p1.x ? NEGB : 0.f, p1.y ? NEGB : 0.f, p1.z ? NEGB : 0.f, p1.w ? NEGB : 0.f};
    *(float4*)(padf + i) = o0;
    *(float4*)(padf + i + 4) = o1;
    return;
  }
  const float* s; bf16* d; int i;
  if (blk < 4096) { s = x; d = xd; i = blk * 2048 + threadIdx.x * 8; }
  else {
    int m = (blk - 4096) >> 9, bi = (blk - 4096) & 511;
    switch (m) {
      case 0:  s = w0; d = d0; break;
      case 1:  s = w1; d = d1; break;
      case 2:  s = w2; d = d2; break;
      default: s = w3; d = d3; break;
    }
    i = bi * 2048 + threadIdx.x * 8;
  }
  float4 v0 = *(const float4*)(s + i);
  float4 v1 = *(const float4*)(s + i + 4);
  bf16x8 o = {(bf16)v0.x, (bf16)v0.y, (bf16)v0.z, (bf16)v0.w,
              (bf16)v1.x, (bf16)v1.y, (bf16)v1.z, (bf16)v1.w};
  *(bf16x8*)(d + i) = o;
}

// ---------------- fine-phase bf16 GEMM core, 128x256, BK=32, triple-buffer -----
// LDS element (r, 16B-chunk j): byte r*64 + (j ^ (r&3))*16 (global_load_lds dest
// linear in tid; source column pre-swizzled). Fragment read (row r, k-chunk
// quad): r*64 + (quad^(r&3))*16.
// OUT_MODE 0: bf16 out head-split [B,H,S,dk]; 1: fp32 flat [M,1024];
// OUT_MODE 2: bf16 out TRANSPOSED head-split [B,H,dk,S] via per-wave LDS transpose.
template <int OUT_MODE>
__device__ __forceinline__ void gemm_fine(const bf16* __restrict__ A,
                                          const bf16* __restrict__ W,
                                          const float* __restrict__ bias,
                                          void* __restrict__ outp,
                                          int bm, int bn, char* smem) {
  const int tid  = threadIdx.x;
  const int lane = tid & 63;
  const int wv   = tid >> 6;
  const int wr   = wv >> 2;            // M half (64 rows)
  const int wc   = wv & 3;             // N quarter (64 cols)
  const int c    = lane & 15;
  const int quad = lane >> 4;

  char* Ab = smem;                     // 3 x 8192
  char* Bb = smem + 24576;             // 3 x 16384

  // staging: thread t owns (row = t>>2, phys chunk = t&3); dest linear t*16,
  // source chunk pre-swizzled: (t&3) ^ (row&3).
  const int sr  = tid >> 2;            // 0..127
  const int sjj = ((tid & 3) ^ (sr & 3)) * 8;
  const bf16* gA = A + (size_t)(bm + sr) * DM + sjj;
  const bf16* gB = W + (size_t)(bn + sr) * DM + sjj;

#define STG(KT, U) {                                                     \
    async16(gA + (size_t)(KT) * 32, Ab + (U) * 8192 + tid * 16);         \
    async16(gB + (size_t)(KT) * 32, Bb + (U) * 16384 + tid * 16);        \
    async16(gB + (size_t)(KT) * 32 + (size_t)128 * DM,                   \
            Bb + (U) * 16384 + 8192 + tid * 16); }

  const int sw = (quad ^ (c & 3)) * 16;
  int aoff[4], boff[4];
#pragma unroll
  for (int i = 0; i < 4; ++i) {
    aoff[i] = (wr * 64 + i * 16 + c) * 64 + sw;
    boff[i] = (wc * 64 + i * 16 + c) * 64 + sw;
  }

  f32x4 acc[4][4] = {};

  // prologue: stage tiles 0,1 (3 loads each); wait tile 0 (tile 1 in flight)
  STG(0, 0) STG(1, 1)
  asm volatile("s_waitcnt vmcnt(3)" ::: "memory");
  __builtin_amdgcn_s_barrier();
  __builtin_amdgcn_sched_barrier(0);

#pragma unroll
  for (int kt = 0; kt < 32; ++kt) {
    const char* Ac = Ab + (kt % 3) * 8192;
    const char* Bc = Bb + (kt % 3) * 16384;
    bf16x8 a[4], b[4];
#pragma unroll
    for (int i = 0; i < 4; ++i) a[i] = *(const bf16x8*)(Ac + aoff[i]);
#pragma unroll
    for (int i = 0; i < 4; ++i) b[i] = *(const bf16x8*)(Bc + boff[i]);
    if (kt + 2 < 32) STG(kt + 2, (kt + 2) % 3)
    __builtin_amdgcn_s_barrier();
    asm volatile("s_waitcnt lgkmcnt(0)" ::: "memory");
    __builtin_amdgcn_sched_barrier(0);
    __builtin_amdgcn_s_setprio(1);
#pragma unroll
    for (int mi = 0; mi < 4; ++mi)
#pragma unroll
      for (int ni = 0; ni < 4; ++ni)
        acc[mi][ni] = __builtin_amdgcn_mfma_f32_16x16x32_bf16(a[mi], b[ni],
                                                              acc[mi][ni], 0, 0, 0);
    __builtin_amdgcn_s_setprio(0);
    // boundary: tile kt+1's 3 loads retired; tile kt+2's 3 stay in flight
    if (kt <= 29)      asm volatile("s_waitcnt vmcnt(3)" ::: "memory");
    else if (kt == 30) asm volatile("s_waitcnt vmcnt(0)" ::: "memory");
    if (kt != 31) {
      __builtin_amdgcn_s_barrier();
      __builtin_amdgcn_sched_barrier(0);
    }
  }
#undef STG

  float bias_r[4];
#pragma unroll
  for (int ni = 0; ni < 4; ++ni) bias_r[ni] = bias[bn + wc * 64 + ni * 16 + c];

  if constexpr (OUT_MODE == 2) {
    // per-wave 64x64 transpose in LDS (pipeline buffers reused; all waves past
    // their last ds_read), then coalesced b128 stores: d-rows contiguous in s.
    __syncthreads();
    bf16* vt = (bf16*)smem + wv * 4608;  // 64*72 elements per wave (8*9216B=72KB)
#pragma unroll
    for (int mi = 0; mi < 4; ++mi)
#pragma unroll
      for (int ni = 0; ni < 4; ++ni) {
        bf16x4 pv = {(bf16)(acc[mi][ni][0] + bias_r[ni]),
                     (bf16)(acc[mi][ni][1] + bias_r[ni]),
                     (bf16)(acc[mi][ni][2] + bias_r[ni]),
                     (bf16)(acc[mi][ni][3] + bias_r[ni])};
        *(bf16x4*)&vt[(ni * 16 + c) * 72 + mi * 16 + quad * 4] = pv;
      }
    const int base = bm + wr * 64;        // s base (2048 % 64 == 0 -> one b)
    const int bb = base >> 11, s0 = base & 2047;
    const int rl = lane >> 3, cl = lane & 7;
#pragma unroll
    for (int it = 0; it < 8; ++it) {
      int d_row = it * 8 + rl;
      bf16x8 v = *(const bf16x8*)&vt[d_row * 72 + cl * 8];
      int n_g = bn + wc * 64 + d_row;
      int hh = n_g >> 6, dd = n_g & 63;
      *(bf16x8*)&((bf16*)outp)[(((size_t)(bb * NH + hh)) * DK + dd) * SEQL + s0 + cl * 8] = v;
    }
    return;
  }

#pragma unroll
  for (int mi = 0; mi < 4; ++mi) {
#pragma unroll
    for (int reg = 0; reg < 4; ++reg) {
      int m_g = bm + wr * 64 + mi * 16 + quad * 4 + reg;
#pragma unroll
      for (int ni = 0; ni < 4; ++ni) {
        int n_g = bn + wc * 64 + ni * 16 + c;
        float v = acc[mi][ni][reg] + bias_r[ni];
        if constexpr (OUT_MODE == 0) {
          int b = m_g >> 11, s = m_g & 2047;
          int h = n_g >> 6, d = n_g & 63;
          ((bf16*)outp)[(((size_t)(b * NH + h) * SEQL + s) << 6) + d] = (bf16)v;
        } else {
          ((float*)outp)[(size_t)m_g * DM + n_g] = v;
        }
      }
    }
  }
}

// QKV: 768 blocks = 3 exact rounds at 1 block/CU (or overlapped at 2/CU).
// XCD chunk z-major: co-resident working set per XCD = X panel (2MB) + one W
// (2MB) = 4MB = one L2.
__global__ __launch_bounds__(512, 4) void qkv_gemm(
    const bf16* __restrict__ X,
    const bf16* __restrict__ Wq, const bf16* __restrict__ Wk, const bf16* __restrict__ Wv,
    const float* __restrict__ bq, const float* __restrict__ bk, const float* __restrict__ bv,
    bf16* __restrict__ Q, bf16* __restrict__ K, bf16* __restrict__ Vt) {
  __shared__ alignas(16) char smem[73728];
  const int f   = blockIdx.x;            // 0..767
  const int xcd = f & 7;
  const int c96 = f >> 3;                // 0..95 within XCD
  const int z   = c96 >> 5;              // 0:Q 1:K 2:V
  const int r   = c96 & 31;
  const int bm  = (xcd * 8 + (r >> 2)) * 128;
  const int bn  = (r & 3) * 256;
  if (z == 0)      gemm_fine<0>(X, Wq, bq, Q,  bm, bn, smem);
  else if (z == 1) gemm_fine<0>(X, Wk, bk, K,  bm, bn, smem);
  else             gemm_fine<2>(X, Wv, bv, Vt, bm, bn, smem);
}

// Out proj: 256 blocks (64 m x 4 n) = exactly 1 round.
__global__ __launch_bounds__(512, 4) void out_gemm(const bf16* __restrict__ A,
                                                   const bf16* __restrict__ W,
                                                   const float* __restrict__ bias,
                                                   float* __restrict__ out) {
  __shared__ alignas(16) char smem[73728];
  const int f   = blockIdx.x;
  const int c32 = f >> 3;
  const int bm  = ((f & 7) * 8 + (c32 >> 2)) * 128;
  const int bn  = (c32 & 3) * 256;
  gemm_fine<1>(A, W, bias, out, bm, bn, smem);
}

// ---------------- flash attention: 8 waves x 32 q-rows, 256-row q-tile ----------
// (unchanged)
__global__ __launch_bounds__(512, 2) void attn_kernel(
    const bf16* __restrict__ Q, const bf16* __restrict__ K,
    const bf16* __restrict__ Vt, const float* __restrict__ padf,
    bf16* __restrict__ O) {
  const int B = blockIdx.x;              // 0..255
  const int bh = (B & 7) + 8 * (B >> 5); // 8 bh per XCD (KV set = 4MB = one L2)
  const int t  = (B >> 3) & 3;           // pair index 0..3
  const int b = bh >> 4, h = bh & 15;
  const int tid  = threadIdx.x;
  const int lane = tid & 63;
  const int wv   = tid >> 6;             // 0..7
  const int c    = lane & 15;
  const int quad = lane >> 4;

  __shared__ bf16 Ks[2][64 * 64];        // [key][d], 128B rows, XOR-3 chunk swz
  __shared__ bf16 Vs[2][64 * 64];        // [d][key], 128B rows, XOR-3 chunk swz
  __shared__ bf16 Pl_all[8][32 * 64];    // per-wave P, 128B rows, XOR-3 chunk swz
  bf16* Pl = &Pl_all[wv][0];

  const bf16* Qh  = Q  + (size_t)bh * SEQL * DK;
  const bf16* Kh  = K  + (size_t)bh * SEQL * DK;
  const bf16* Vth = Vt + (size_t)bh * DK * SEQL;
  const float* pb = padf + b * SEQL;

  const int sr = tid >> 3;                      // 0..63
  const int sj = ((tid & 7) ^ (sr & 7)) * 8;    // swizzled source element offset
  const bf16* gK = Kh  + (size_t)sr * DK   + sj;
  const bf16* gV = Vth + (size_t)sr * SEQL + sj;
  bf16* lK0 = &Ks[0][tid * 8]; bf16* lK1 = &Ks[1][tid * 8];
  bf16* lV0 = &Vs[0][tid * 8]; bf16* lV1 = &Vs[1][tid * 8];

  const float sc = 0.1803368801111204f;  // log2(e) / sqrt(64)

  for (int pass = 0; pass < 2; ++pass) {
    const int qt  = pass ? 7 - t : t;    // 256-row q-tile index
    const int R   = qt * 256 + wv * 32;  // wave's first q row
    const int nkt = (qt + 1) * 4;        // 64-key tiles

    bf16x8 Qf[2][2];
#pragma unroll
    for (int qg = 0; qg < 2; ++qg)
#pragma unroll
      for (int kh = 0; kh < 2; ++kh)
        Qf[qg][kh] = *(const bf16x8*)&Qh[(size_t)(R + qg * 16 + c) * DK + kh * 32 + quad * 8];

    f32x4 Oc[2][4] = {};
    float ls[2] = {0.f, 0.f};

    __syncthreads();
    async16(gK, lK0);
    async16(gV, lV0);

    for (int kt = 0; kt < nkt; ++kt) {
      const int cur = kt & 1;
      const int kb = kt * 64;
      __syncthreads();

      if (kt + 1 < nkt) {
        async16(gK + (size_t)(kt + 1) * 64 * DK, cur ? lK0 : lK1);
        async16(gV + (size_t)(kt + 1) * 64,      cur ? lV0 : lV1);
      }
      if (kb > R + 31) continue;

      float4 bc[4];
#pragma unroll
      for (int kf = 0; kf < 4; ++kf)
        bc[kf] = *(const float4*)&pb[kb + kf * 16 + quad * 4];

      const bf16* Kc = cur ? Ks[1] : Ks[0];
      const bf16* Vc = cur ? Vs[1] : Vs[0];

      bf16x8 Kf[4][2], Vf[4][2];
#pragma unroll
      for (int kf = 0; kf < 4; ++kf)
#pragma unroll
        for (int kh = 0; kh < 2; ++kh)
          Kf[kf][kh] = *(const bf16x8*)&Kc[(kf * 16 + c) * 64 + (((kh * 4 + quad) ^ (c & 7)) * 8)];
#pragma unroll
      for (int df = 0; df < 4; ++df)
#pragma unroll
        for (int kv = 0; kv < 2; ++kv)
          Vf[df][kv] = *(const bf16x8*)&Vc[(df * 16 + c) * 64 + (((kv * 4 + quad) ^ (c & 7)) * 8)];

      f32x4 st[2][4] = {};
#pragma unroll
      for (int qg = 0; qg < 2; ++qg)
#pragma unroll
        for (int kh = 0; kh < 2; ++kh)
#pragma unroll
          for (int kf = 0; kf < 4; ++kf)
            st[qg][kf] = __builtin_amdgcn_mfma_f32_16x16x32_bf16(Kf[kf][kh], Qf[qg][kh],
                                                                 st[qg][kf], 0, 0, 0);

      const bool dg = (kb + 63 > R);
#pragma unroll
      for (int qg = 0; qg < 2; ++qg) {
        const int qrow = R + qg * 16 + c;
#pragma unroll
        for (int kf = 0; kf < 4; ++kf) {
          const float* bv4 = (const float*)&bc[kf];
          float p4[4];
#pragma unroll
          for (int r = 0; r < 4; ++r) {
            float e = __builtin_amdgcn_exp2f(__builtin_fmaf(st[qg][kf][r], sc, bv4[r]));
            if (dg && (kb + kf * 16 + quad * 4 + r > qrow)) e = 0.f;
            p4[r] = e;
            ls[qg] += e;
          }
          bf16x4 pk = {(bf16)p4[0], (bf16)p4[1], (bf16)p4[2], (bf16)p4[3]};
          *(bf16x4*)&Pl[(qg * 16 + c) * 64 +
                        (((kf * 2 + (quad >> 1)) ^ (c & 7)) * 8) + (quad & 1) * 4] = pk;
        }
      }

#pragma unroll
      for (int qg = 0; qg < 2; ++qg)
#pragma unroll
        for (int kv = 0; kv < 2; ++kv) {
          bf16x8 af = *(const bf16x8*)&Pl[(qg * 16 + c) * 64 +
                                          (((kv * 4 + quad) ^ (c & 7)) * 8)];
#pragma unroll
          for (int df = 0; df < 4; ++df)
            Oc[qg][df] = __builtin_amdgcn_mfma_f32_16x16x32_bf16(af, Vf[df][kv],
                                                                 Oc[qg][df], 0, 0, 0);
        }
    }

#pragma unroll
    for (int qg = 0; qg < 2; ++qg) {
      float l = ls[qg];
      l += __shfl_xor(l, 16);
      l += __shfl_xor(l, 32);
      float linv = (l > 0.f) ? 1.f / l : 0.f;
      float lr[4];
#pragma unroll
      for (int r = 0; r < 4; ++r) lr[r] = __shfl(linv, quad * 4 + r);
#pragma unroll
      for (int r = 0; r < 4; ++r) {
        size_t row = (size_t)(b * SEQL + R + qg * 16 + quad * 4 + r) * DM + h * DK;
#pragma unroll
        for (int df = 0; df < 4; ++df)
          O[row + df * 16 + c] = (bf16)(Oc[qg][df][r] * lr[r]);
      }
    }
  }
}

// ---------------- launch ----------------
extern "C" void kernel_launch(void* const* d_in, const int* in_sizes, int n_in,
                              void* d_out, int out_size, void* d_ws, size_t ws_size,
                              hipStream_t stream) {
  const float* x   = (const float*)d_in[0];
  const int*   pad = (const int*)d_in[1];
  const float* Wq  = (const float*)d_in[2];
  const float* bq  = (const float*)d_in[3];
  const float* Wk  = (const float*)d_in[4];
  const float* bk  = (const float*)d_in[5];
  const float* Wv  = (const float*)d_in[6];
  const float* bv  = (const float*)d_in[7];
  const float* Wo  = (const float*)d_in[8];
  const float* bo  = (const float*)d_in[9];
  float* out = (float*)d_out;

  const size_t SZ_X = (size_t)NTOK * DM * 2;  // 16 MB
  const size_t SZ_W = (size_t)DM * DM * 2;    // 2 MB
  char* ws = (char*)d_ws;
  bf16* Xb  = (bf16*)ws;  ws += SZ_X;
  bf16* Wqb = (bf16*)ws;  ws += SZ_W;
  bf16* Wkb = (bf16*)ws;  ws += SZ_W;
  bf16* Wvb = (bf16*)ws;  ws += SZ_W;
  bf16* Wob = (bf16*)ws;  ws += SZ_W;
  bf16* Qb  = (bf16*)ws;  ws += SZ_X;
  bf16* Kb  = (bf16*)ws;  ws += SZ_X;
  bf16* Vtb = (bf16*)ws;  ws += SZ_X;   // [B,H,dk,S]
  bf16* Ob  = (bf16*)ws;  ws += SZ_X;
  float* padfb = (float*)ws; ws += (size_t)NTOK * 4;

  cvt_all<<<6148, 256, 0, stream>>>(x, Wq, Wk, Wv, Wo, pad,
                                    Xb, Wqb, Wkb, Wvb, Wob, padfb);
  qkv_gemm<<<768, 512, 0, stream>>>(Xb, Wqb, Wkb, Wvb, bq, bk, bv, Qb, Kb, Vtb);
  attn_kernel<<<256, 512, 0, stream>>>(Qb, Kb, Vtb, padfb, Ob);
  out_gemm<<<256, 512, 0, stream>>>(Ob, Wob, bo, out);
}